// Round 5
// baseline (2589.244 us; speedup 1.0000x reference)
//
#include <hip/hip_runtime.h>
#include <hip/hip_bf16.h>

// LSTM: B=64, T=512, I=256, H=1024, O=1.
// Persistent cooperative kernel: 256 blocks = 4 batch-groups x 64 unit-groups.
// R5: parallel epilogue. Phase A: waves 0-3 reduce one gate each (b128 LDS).
// Phase B: 256 threads, one (batch,unit) each -> 1 nonlinearity set/thread,
// per-thread cell state, 2B coalesced h store, per-wave sub-flags (4/producer,
// one 64B line). Pipelined 2-deep flag poll (no s_sleep). Single red buffer.

typedef __bf16 bf16_t;
typedef bf16_t b16x8 __attribute__((ext_vector_type(8)));
typedef float  f32x4 __attribute__((ext_vector_type(4)));

#define TQ 512
#define IQ 256
#define HQ 1024

union U8 { b16x8 b; unsigned long long q[2]; unsigned short u[8]; };

__device__ __forceinline__ float bf2f(unsigned short s) {
    return __uint_as_float(((unsigned)s) << 16);
}
__device__ __forceinline__ unsigned short f2bf(float f) {
    unsigned u = __float_as_uint(f);
    u += 0x7fff + ((u >> 16) & 1);   // RNE
    return (unsigned short)(u >> 16);
}
__device__ __forceinline__ b16x8 cvt84(float4 a, float4 b) {
    U8 r;
    r.u[0] = f2bf(a.x); r.u[1] = f2bf(a.y); r.u[2] = f2bf(a.z); r.u[3] = f2bf(a.w);
    r.u[4] = f2bf(b.x); r.u[5] = f2bf(b.y); r.u[6] = f2bf(b.z); r.u[7] = f2bf(b.w);
    return r.b;
}
// agent-scope 16B load as 2x8B atomic loads — bypasses non-coherent L1/L2
__device__ __forceinline__ b16x8 load_h16(const unsigned short* p) {
    U8 r;
    r.q[0] = __hip_atomic_load((const unsigned long long*)p,
                               __ATOMIC_RELAXED, __HIP_MEMORY_SCOPE_AGENT);
    r.q[1] = __hip_atomic_load((const unsigned long long*)(p + 4),
                               __ATOMIC_RELAXED, __HIP_MEMORY_SCOPE_AGENT);
    return r.b;
}
__device__ __forceinline__ unsigned ld_flag(const unsigned int* p) {
    return __hip_atomic_load(p, __ATOMIC_RELAXED, __HIP_MEMORY_SCOPE_AGENT);
}
__device__ __forceinline__ float sigm(float x) {
    return 1.f / (1.f + __expf(-x));
}
__device__ __forceinline__ float tanh_f(float v) {
    float x = fminf(fmaxf(v, -15.f), 15.f);
    float e = __expf(2.f * x);
    return (e - 1.f) / (e + 1.f);
}

__launch_bounds__(512, 2)
__global__ void lstm_persist(const float* __restrict__ x,
                             const float* __restrict__ Wih,
                             const float* __restrict__ Whh,
                             const float* __restrict__ bih,
                             const float* __restrict__ bhh,
                             const float* __restrict__ fcW,
                             const float* __restrict__ fcb,
                             float* __restrict__ out,
                             unsigned short* __restrict__ hbuf, // [2][4][16][1024] bf16
                             unsigned int* __restrict__ bar)    // [4][64][16] dwords
{
    __shared__ float red[8192];    // 32KB per-wave partials [ww][g][lane][reg]
    __shared__ float gbuf[1024];   // 4KB reduced gates [g][b*16+u]

    const int tid  = threadIdx.x;
    const int w    = tid >> 6;        // wave 0..7
    const int lane = tid & 63;
    const int bid  = blockIdx.x;
    const int bg   = bid & 3;         // batch group (16 batches)
    const int ug   = bid >> 2;        // unit group (16 hidden units)

    const int l16  = lane & 15;
    const int quad = lane >> 4;

    // ---- one-time: load weight fragments into registers (bf16) ----
    // B^T-fragment: lane holds W[row = base + l16][k0 + quad*8 + j]
    b16x8 wih[4];        // x part: this wave's x-kstep
    b16x8 whh[4][4];     // h part: 4 ksteps x 4 gates
    {
        const int koff = quad * 8;
        #pragma unroll
        for (int g = 0; g < 4; ++g) {
            int row = g * HQ + ug * 16 + l16;
            const float* p = Wih + (size_t)row * IQ + w * 32 + koff;
            float4 a = *(const float4*)p;
            float4 b = *(const float4*)(p + 4);
            wih[g] = cvt84(a, b);
            #pragma unroll
            for (int j = 0; j < 4; ++j) {
                int k0 = (w * 4 + j) * 32 + koff;
                const float* q = Whh + (size_t)row * HQ + k0;
                float4 c = *(const float4*)q;
                float4 d = *(const float4*)(q + 4);
                whh[j][g] = cvt84(c, d);
            }
        }
    }

    // Phase-B ownership (threads 0..255): b = tid>>4, u = tid&15
    float c_st = 0.f;
    float bias_r[4] = {0.f, 0.f, 0.f, 0.f};
    if (tid < 256) {
        int u = tid & 15;
        #pragma unroll
        for (int g = 0; g < 4; ++g) {
            int gr = g * HQ + ug * 16 + u;
            bias_r[g] = bih[gr] + bhh[gr];
        }
    }

    // flags: fl[pg*16 + sub] = step counter of producer pg, epilogue wave sub
    unsigned int* fl = bar + (size_t)bg * 1024;   // 64 producers x 64B
    const unsigned int* myfl =
        fl + (size_t)(8 * w + ((lane & 31) >> 2)) * 16 + (lane & 3);

    // software-pipelined x load (step 0)
    const float* xbase = x + ((size_t)(bg * 16 + l16) * TQ) * IQ + w * 32 + quad * 8;
    float4 xa = *(const float4*)(xbase);
    float4 xb = *(const float4*)(xbase + 4);

    for (int t = 0; t < TQ; ++t) {
        const int p = t & 1;

        // ---- h-independent shadow work ----
        b16x8 ax = cvt84(xa, xb);
        f32x4 acc[4];
        #pragma unroll
        for (int g = 0; g < 4; ++g) {
            f32x4 z = {0.f, 0.f, 0.f, 0.f};
            acc[g] = __builtin_amdgcn_mfma_f32_16x16x32_bf16(ax, wih[g], z, 0, 0, 0);
        }

        // ---- pipelined 2-deep poll on this K-slice's producers ----
        if (t) {
            int tv = t;
            unsigned va = ld_flag(myfl);
            unsigned vb = ld_flag(myfl);
            for (;;) {
                if (__all((int)va >= tv)) break;
                va = ld_flag(myfl);
                if (__all((int)vb >= tv)) break;
                vb = ld_flag(myfl);
            }
        }

        // ---- h A-fragments + h MFMAs ----
        const unsigned short* hread = hbuf + ((size_t)p * 4 + bg) * (16 * HQ);
        b16x8 ah[4];
        #pragma unroll
        for (int j = 0; j < 4; ++j)
            ah[j] = load_h16(hread + (size_t)l16 * HQ + (w * 4 + j) * 32 + quad * 8);
        #pragma unroll
        for (int j = 0; j < 4; ++j) {
            #pragma unroll
            for (int g = 0; g < 4; ++g)
                acc[g] = __builtin_amdgcn_mfma_f32_16x16x32_bf16(ah[j], whh[j][g], acc[g], 0, 0, 0);
        }

        // ---- write per-wave partials ----
        #pragma unroll
        for (int g = 0; g < 4; ++g)
            *(f32x4*)&red[((w * 4 + g) * 64 + lane) * 4] = acc[g];
        __syncthreads();   // B1

        // ---- phase A: wave g reduces gate g (waves 0-3) ----
        if (w < 4) {
            f32x4 s = *(const f32x4*)&red[((0 * 4 + w) * 64 + lane) * 4];
            #pragma unroll
            for (int ww = 1; ww < 8; ++ww)
                s += *(const f32x4*)&red[((ww * 4 + w) * 64 + lane) * 4];
            // value s[r] is gate w, batch quad*4+r, unit l16
            #pragma unroll
            for (int r = 0; r < 4; ++r)
                gbuf[w * 256 + quad * 64 + r * 16 + l16] = s[r];
        } else {
            // x prefetch t+1 (waves 4-7)
            size_t nt = (t + 1 < TQ) ? (size_t)(t + 1) * IQ : (size_t)t * IQ;
            xa = *(const float4*)(xbase + nt);
            xb = *(const float4*)(xbase + nt + 4);
        }
        __syncthreads();   // B2

        // ---- phase B: 256 threads, one (b,u) each ----
        if (tid < 256) {
            int b = tid >> 4, u = tid & 15;
            float gi = gbuf[0 * 256 + tid] + bias_r[0];
            float gf = gbuf[1 * 256 + tid] + bias_r[1];
            float gg = gbuf[2 * 256 + tid] + bias_r[2];
            float go = gbuf[3 * 256 + tid] + bias_r[3];
            float i_s = sigm(gi);
            float f_s = sigm(gf);
            float g_t = tanh_f(gg);
            float o_s = sigm(go);
            float c = f_s * c_st + i_s * g_t;
            c_st = c;
            float h = o_s * tanh_f(c);
            unsigned short* hw = hbuf + ((size_t)(p ^ 1) * 4 + bg) * (16 * HQ)
                               + (size_t)b * HQ + ug * 16 + u;
            __hip_atomic_store(hw, f2bf(h),
                               __ATOMIC_RELAXED, __HIP_MEMORY_SCOPE_AGENT);
            // drain this wave's h stores, then signal its sub-flag
            asm volatile("s_waitcnt vmcnt(0)" ::: "memory");
            if (lane == 0)
                __hip_atomic_store(fl + (size_t)ug * 16 + w, (unsigned)(t + 1),
                                   __ATOMIC_RELAXED, __HIP_MEMORY_SCOPE_AGENT);
            asm volatile("" ::: "memory");   // keep x prefetch out of the drain
            // x prefetch t+1 (waves 0-3)
            size_t nt = (t + 1 < TQ) ? (size_t)(t + 1) * IQ : (size_t)t * IQ;
            xa = *(const float4*)(xbase + nt);
            xb = *(const float4*)(xbase + nt + 4);
        }
    }

    // ---- final projection: out = tanh(h_T) @ fcW^T + fcb (blocks 0..3) ----
    if (bid < 4) {
        {   // all 8 waves collectively verify all 64 producers finished
            unsigned va = ld_flag(myfl);
            while (!__all((int)va >= TQ))
                va = ld_flag(myfl);
        }
        __syncthreads();
        const unsigned short* hl = hbuf + (size_t)bg * (16 * HQ); // T even -> buf0
        float fb = fcb[0];
        #pragma unroll
        for (int r = 0; r < 2; ++r) {
            int b = w * 2 + r;
            float s = 0.f;
            #pragma unroll
            for (int j = 0; j < 16; ++j) {
                int u = j * 64 + lane;
                unsigned short hv = __hip_atomic_load(hl + b * HQ + u,
                                                      __ATOMIC_RELAXED,
                                                      __HIP_MEMORY_SCOPE_AGENT);
                s += tanh_f(bf2f(hv)) * fcW[u];
            }
            #pragma unroll
            for (int off = 32; off > 0; off >>= 1)
                s += __shfl_down(s, off);
            if (lane == 0) out[bg * 16 + b] = s + fb;
        }
    }
}

extern "C" void kernel_launch(void* const* d_in, const int* in_sizes, int n_in,
                              void* d_out, int out_size, void* d_ws, size_t ws_size,
                              hipStream_t stream) {
    (void)in_sizes; (void)n_in; (void)out_size; (void)ws_size;
    const float* x   = (const float*)d_in[0];
    const float* Wih = (const float*)d_in[1];
    const float* Whh = (const float*)d_in[2];
    const float* bih = (const float*)d_in[3];
    const float* bhh = (const float*)d_in[4];
    const float* fcW = (const float*)d_in[5];
    const float* fcb = (const float*)d_in[6];
    float* out = (float*)d_out;

    unsigned short* hbuf = (unsigned short*)d_ws;                       // 262144 B
    unsigned int*   bar  = (unsigned int*)((char*)d_ws + 262144);       // 16384 B

    hipMemsetAsync(d_ws, 0, 262144 + 16384, stream);

    void* args[] = { &x, &Wih, &Whh, &bih, &bhh, &fcW, &fcb, &out, &hbuf, &bar };
    hipLaunchCooperativeKernel(reinterpret_cast<void*>(lstm_persist),
                               dim3(256), dim3(512), args, 0, stream);
}